// Round 2
// baseline (957.332 us; speedup 1.0000x reference)
//
#include <hip/hip_runtime.h>
#include <stdint.h>

#define T_SEQ 2048
#define NFEAT 512
#define NHEAD 8
#define DHEAD 64
#define NROWS 8192  // B*T
#define QT 16      // q-rows per attention block

using short8  = __attribute__((ext_vector_type(8))) short;
using floatx4 = __attribute__((ext_vector_type(4))) float;

__device__ __forceinline__ unsigned short f2bf(float x){
  unsigned u = __builtin_bit_cast(unsigned, x);
  unsigned r = (u + 0x7fffu + ((u >> 16) & 1u)) >> 16;  // RNE
  return (unsigned short)r;
}
__device__ __forceinline__ float bf2f(unsigned short u){
  return __builtin_bit_cast(float, ((unsigned)u) << 16);
}

// ---------------- weight prep: hi/lo bf16 split ----------------
__global__ __launch_bounds__(256) void prep_w(
    const float* __restrict__ Wq, const float* __restrict__ Wk,
    const float* __restrict__ Wv, const float* __restrict__ Wo,
    unsigned short* __restrict__ Wqh, unsigned short* __restrict__ Wql,
    unsigned short* __restrict__ Wkh, unsigned short* __restrict__ Wkl,
    unsigned short* __restrict__ Wvh, unsigned short* __restrict__ Woh){
  int i = blockIdx.x * 256 + threadIdx.x;
  if (i >= NFEAT * NFEAT) return;
  float q = Wq[i], k = Wk[i], v = Wv[i], o = Wo[i];
  unsigned short qh = f2bf(q), kh = f2bf(k);
  Wqh[i] = qh; Wql[i] = f2bf(q - bf2f(qh));
  Wkh[i] = kh; Wkl[i] = f2bf(k - bf2f(kh));
  Wvh[i] = f2bf(v); Woh[i] = f2bf(o);
}

// ---------------- layernorm + hi/lo split, one wave per row ----------------
__global__ __launch_bounds__(256) void ln_split(
    const float* __restrict__ x, const float* __restrict__ gamma,
    const float* __restrict__ beta,
    unsigned short* __restrict__ xh, unsigned short* __restrict__ xl){
  int row  = blockIdx.x * 4 + (threadIdx.x >> 6);
  int lane = threadIdx.x & 63;
  const float* xr = x + (size_t)row * NFEAT + lane * 8;
  float4 a = *(const float4*)xr;
  float4 b = *(const float4*)(xr + 4);
  float v[8] = {a.x, a.y, a.z, a.w, b.x, b.y, b.z, b.w};
  float s = 0.f, sq = 0.f;
#pragma unroll
  for (int e = 0; e < 8; ++e){ s += v[e]; sq += v[e] * v[e]; }
#pragma unroll
  for (int m = 1; m < 64; m <<= 1){ s += __shfl_xor(s, m); sq += __shfl_xor(sq, m); }
  float mu  = s * (1.f / NFEAT);
  float var = fmaxf(sq * (1.f / NFEAT) - mu * mu, 0.f);
  float rs  = rsqrtf(var + 1e-5f);
  int c0 = lane * 8;
  short8 ph, pl;
#pragma unroll
  for (int e = 0; e < 8; ++e){
    float xn = (v[e] - mu) * rs * gamma[c0 + e] + beta[c0 + e];
    unsigned short hh = f2bf(xn);
    ph[e] = (short)hh;
    pl[e] = (short)f2bf(xn - bf2f(hh));
  }
  *(short8*)(xh + (size_t)row * NFEAT + c0) = ph;
  *(short8*)(xl + (size_t)row * NFEAT + c0) = pl;
}

// ---------------- NT GEMM: Y[m][n] = sum_k A[m][k]*B[n][k], M=8192,N=512,K=512
// SPLIT: 3-term hi/lo product for accuracy. OMODE: 0=[b,h,t,d] bf16,
// 1=[b,h,d,t] bf16 (transposed V), 2=f32 [m][n]
template<bool SPLIT, int OMODE>
__global__ __launch_bounds__(256) void gemm_nt(
    const unsigned short* __restrict__ Ah, const unsigned short* __restrict__ Al,
    const unsigned short* __restrict__ Bh, const unsigned short* __restrict__ Bl,
    void* __restrict__ outp){
  int lane = threadIdx.x & 63;
  int wid  = threadIdx.x >> 6;
  int row0 = blockIdx.x * 128 + (wid >> 1) * 64;
  int col0 = blockIdx.y * 128 + (wid & 1) * 64;
  int lr = lane & 15;
  int lk = (lane >> 4) * 8;
  floatx4 acc[4][4] = {};
  for (int k0 = 0; k0 < NFEAT; k0 += 32){
    short8 aH[4], bH[4], aL[4], bL[4];
#pragma unroll
    for (int r = 0; r < 4; ++r){
      size_t off = (size_t)(row0 + r * 16 + lr) * NFEAT + k0 + lk;
      aH[r] = *(const short8*)(Ah + off);
      if (SPLIT) aL[r] = *(const short8*)(Al + off);
    }
#pragma unroll
    for (int c = 0; c < 4; ++c){
      size_t off = (size_t)(col0 + c * 16 + lr) * NFEAT + k0 + lk;
      bH[c] = *(const short8*)(Bh + off);
      if (SPLIT) bL[c] = *(const short8*)(Bl + off);
    }
#pragma unroll
    for (int r = 0; r < 4; ++r)
#pragma unroll
      for (int c = 0; c < 4; ++c){
        acc[r][c] = __builtin_amdgcn_mfma_f32_16x16x32_bf16(aH[r], bH[c], acc[r][c], 0, 0, 0);
        if (SPLIT){
          acc[r][c] = __builtin_amdgcn_mfma_f32_16x16x32_bf16(aH[r], bL[c], acc[r][c], 0, 0, 0);
          acc[r][c] = __builtin_amdgcn_mfma_f32_16x16x32_bf16(aL[r], bH[c], acc[r][c], 0, 0, 0);
        }
      }
  }
  int rb = (lane >> 4) * 4;
#pragma unroll
  for (int r = 0; r < 4; ++r)
#pragma unroll
    for (int c = 0; c < 4; ++c)
#pragma unroll
      for (int j = 0; j < 4; ++j){
        int m = row0 + r * 16 + rb + j;
        int n = col0 + c * 16 + lr;
        float val = acc[r][c][j];
        if (OMODE == 0){
          int bb = m >> 11, t = m & 2047, h = n >> 6, d = n & 63;
          ((unsigned short*)outp)[(((size_t)(bb * NHEAD + h)) * T_SEQ + t) * DHEAD + d] = f2bf(val);
        } else if (OMODE == 1){
          int bb = m >> 11, t = m & 2047, h = n >> 6, d = n & 63;
          ((unsigned short*)outp)[(((size_t)(bb * NHEAD + h)) * DHEAD + d) * T_SEQ + t] = f2bf(val);
        } else {
          ((float*)outp)[(size_t)m * NFEAT + n] = val;
        }
      }
}

// ---------------- fused attention per (b, h, 16-row q-tile) ----------------
// Static 64 KB LDS. P stored bf16 [16][2048], XOR-swizzled by row (bits 4-6).
// First 1 KB is transiently used as the (max,sum) cross-wave reduce array.
#define SWZB(row, cb) ((((row) * 4096) + (cb)) ^ (((row) & 7) << 4))

__global__ __launch_bounds__(512) void attn_fused(
    const unsigned short* __restrict__ qb, const unsigned short* __restrict__ kb,
    const unsigned short* __restrict__ vt, const unsigned char* __restrict__ maskp,
    float* __restrict__ attn_out, unsigned short* __restrict__ ctx){
  __shared__ char lds[65536];
  int b = blockIdx.z, h = blockIdx.y, qt = blockIdx.x;
  int tid = threadIdx.x;
  int w = tid >> 6, lane = tid & 63;
  int lr = lane & 15, lhi = lane >> 4;
  int qbase = qt * QT;
  size_t hoff = (size_t)(b * NHEAD + h) * T_SEQ * DHEAD;

  // Q fragments (A operand): row=lane&15, k=(lane>>4)*8+i
  short8 aq[2];
#pragma unroll
  for (int ks = 0; ks < 2; ++ks)
    aq[ks] = *(const short8*)(qb + hoff + (size_t)(qbase + lr) * DHEAD + ks * 32 + lhi * 8);

  // ---- QK^T: wave w covers k-columns [w*256, w*256+256), scores stay f32 in regs
  floatx4 acc[16];
#pragma unroll
  for (int kc = 0; kc < 16; ++kc){
    int kcol0 = w * 256 + kc * 16;
    const unsigned short* krow = kb + hoff + (size_t)(kcol0 + lr) * DHEAD + lhi * 8;
    short8 bk0 = *(const short8*)krow;
    short8 bk1 = *(const short8*)(krow + 32);
    floatx4 a = {};
    a = __builtin_amdgcn_mfma_f32_16x16x32_bf16(aq[0], bk0, a, 0, 0, 0);
    a = __builtin_amdgcn_mfma_f32_16x16x32_bf16(aq[1], bk1, a, 0, 0, 0);
    acc[kc] = a * 0.125f;
  }

  // ---- mask (True = -inf). acc[kc][j]: row=lhi*4+j, col=w*256+kc*16+lr
#pragma unroll
  for (int j = 0; j < 4; ++j){
    int row = lhi * 4 + j;
    const unsigned char* mrow = maskp + ((size_t)b * T_SEQ + qbase + row) * T_SEQ;
#pragma unroll
    for (int kc = 0; kc < 16; ++kc){
      if (mrow[w * 256 + kc * 16 + lr])
        acc[kc][j] = -__builtin_inff();
    }
  }

  // ---- wave-local (max, sum) per row, then cross-wave merge via LDS
  float Mj[4], INVj[4];
  {
    float2* red = (float2*)lds;  // [8 waves][16 rows]
    float mloc[4], sloc[4];
#pragma unroll
    for (int j = 0; j < 4; ++j){
      float m = acc[0][j];
#pragma unroll
      for (int kc = 1; kc < 16; ++kc) m = fmaxf(m, acc[kc][j]);
#pragma unroll
      for (int mk = 1; mk < 16; mk <<= 1) m = fmaxf(m, __shfl_xor(m, mk));
      m = fmaxf(m, -1e30f);  // guard fully-masked slice
      float s = 0.f;
#pragma unroll
      for (int kc = 0; kc < 16; ++kc) s += __expf(acc[kc][j] - m);
#pragma unroll
      for (int mk = 1; mk < 16; mk <<= 1) s += __shfl_xor(s, mk);
      mloc[j] = m; sloc[j] = s;
    }
    if (lr == 0){
#pragma unroll
      for (int j = 0; j < 4; ++j){
        float2 t; t.x = mloc[j]; t.y = sloc[j];
        red[w * 16 + lhi * 4 + j] = t;
      }
    }
    __syncthreads();
#pragma unroll
    for (int j = 0; j < 4; ++j){
      int row = lhi * 4 + j;
      float M = -1e30f, D = 0.f;
#pragma unroll
      for (int w2 = 0; w2 < 8; ++w2){
        float2 t = red[w2 * 16 + row];
        float mn = fmaxf(M, t.x);
        D = D * __expf(M - mn) + t.y * __expf(t.x - mn);
        M = mn;
      }
      Mj[j] = M; INVj[j] = 1.0f / D;
    }
    __syncthreads();  // reduce area reads done before P overwrites it
  }

  // ---- write P (bf16) into swizzled LDS
#pragma unroll
  for (int j = 0; j < 4; ++j){
    int row = lhi * 4 + j;
#pragma unroll
    for (int kc = 0; kc < 16; ++kc){
      float pv = __expf(acc[kc][j] - Mj[j]) * INVj[j];
      int col = w * 256 + kc * 16 + lr;
      *(unsigned short*)(lds + SWZB(row, col * 2)) = f2bf(pv);
    }
  }
  __syncthreads();

  // ---- attn output: read P back vectorized, store f32 coalesced
  {
#pragma unroll
    for (int rr = 0; rr < 2; ++rr){
      int row = w * 2 + rr;
      float* arow = attn_out + ((size_t)(b * NHEAD + h) * T_SEQ + qbase + row) * T_SEQ;
#pragma unroll
      for (int it = 0; it < 4; ++it){
        int cb = it * 1024 + lane * 16;
        short8 pv8 = *(const short8*)(lds + SWZB(row, cb));
        float4 f0, f1;
        f0.x = bf2f((unsigned short)pv8[0]); f0.y = bf2f((unsigned short)pv8[1]);
        f0.z = bf2f((unsigned short)pv8[2]); f0.w = bf2f((unsigned short)pv8[3]);
        f1.x = bf2f((unsigned short)pv8[4]); f1.y = bf2f((unsigned short)pv8[5]);
        f1.z = bf2f((unsigned short)pv8[6]); f1.w = bf2f((unsigned short)pv8[7]);
        float* dst = arow + it * 512 + lane * 8;
        *(float4*)dst = f0;
        *(float4*)(dst + 4) = f1;
      }
    }
  }

  // ---- PV: wave w covers t-range [w*256, w*256+256); partial [16][64]
  floatx4 accO[4] = {};
  const unsigned short* vbase = vt + (size_t)(b * NHEAD + h) * DHEAD * T_SEQ;
#pragma unroll
  for (int kc = 0; kc < 8; ++kc){
    int t0 = w * 256 + kc * 32 + lhi * 8;
    short8 pa = *(const short8*)(lds + SWZB(lr, t0 * 2));
    short8 bv[4];
#pragma unroll
    for (int dc = 0; dc < 4; ++dc)
      bv[dc] = *(const short8*)(vbase + (size_t)(dc * 16 + lr) * T_SEQ + t0);
#pragma unroll
    for (int dc = 0; dc < 4; ++dc)
      accO[dc] = __builtin_amdgcn_mfma_f32_16x16x32_bf16(pa, bv[dc], accO[dc], 0, 0, 0);
  }
  __syncthreads();

  // ---- cross-wave reduce of O partials via LDS: [8][16][64] f32 = 32 KB
  {
    float* op = (float*)lds + w * 1024;
#pragma unroll
    for (int dc = 0; dc < 4; ++dc)
#pragma unroll
      for (int j = 0; j < 4; ++j)
        op[(lhi * 4 + j) * 64 + dc * 16 + lr] = accO[dc][j];
  }
  __syncthreads();
  {
    const float* lf = (const float*)lds;
#pragma unroll
    for (int half = 0; half < 2; ++half){
      int e = tid + half * 512;
      float s = 0.f;
#pragma unroll
      for (int w2 = 0; w2 < 8; ++w2) s += lf[w2 * 1024 + e];
      int row = e >> 6, d = e & 63;
      ctx[((size_t)b * T_SEQ + qbase + row) * NFEAT + h * DHEAD + d] = f2bf(s);
    }
  }
}

// ---------------- host launch ----------------
extern "C" void kernel_launch(void* const* d_in, const int* in_sizes, int n_in,
                              void* d_out, int out_size, void* d_ws, size_t ws_size,
                              hipStream_t stream){
  const float* query = (const float*)d_in[0];
  const unsigned char* mask = (const unsigned char*)d_in[1];
  const float* gamma = (const float*)d_in[2];
  const float* beta  = (const float*)d_in[3];
  const float* Wq = (const float*)d_in[4];
  const float* Wk = (const float*)d_in[5];
  const float* Wv = (const float*)d_in[6];
  const float* Wo = (const float*)d_in[7];

  char* p = (char*)d_ws;
  auto alloc = [&](size_t bytes){ char* r = p; p += (bytes + 255) & ~(size_t)255; return r; };
  unsigned short* xh  = (unsigned short*)alloc((size_t)NROWS * NFEAT * 2);
  unsigned short* xl  = (unsigned short*)alloc((size_t)NROWS * NFEAT * 2);
  unsigned short* Wqh = (unsigned short*)alloc((size_t)NFEAT * NFEAT * 2);
  unsigned short* Wql = (unsigned short*)alloc((size_t)NFEAT * NFEAT * 2);
  unsigned short* Wkh = (unsigned short*)alloc((size_t)NFEAT * NFEAT * 2);
  unsigned short* Wkl = (unsigned short*)alloc((size_t)NFEAT * NFEAT * 2);
  unsigned short* Wvh = (unsigned short*)alloc((size_t)NFEAT * NFEAT * 2);
  unsigned short* Woh = (unsigned short*)alloc((size_t)NFEAT * NFEAT * 2);
  unsigned short* qbf = (unsigned short*)alloc((size_t)NROWS * NFEAT * 2);
  unsigned short* kbf = (unsigned short*)alloc((size_t)NROWS * NFEAT * 2);
  unsigned short* vtb = (unsigned short*)alloc((size_t)NROWS * NFEAT * 2);
  unsigned short* ctx = xh;  // xh dead after projections; reuse as ctx

  float* xout     = (float*)d_out;
  float* attn_out = (float*)d_out + (size_t)NROWS * NFEAT;

  prep_w<<<dim3((NFEAT * NFEAT + 255) / 256), 256, 0, stream>>>(
      Wq, Wk, Wv, Wo, Wqh, Wql, Wkh, Wkl, Wvh, Woh);
  ln_split<<<dim3(NROWS / 4), 256, 0, stream>>>(query, gamma, beta, xh, xl);
  gemm_nt<true, 0><<<dim3(64, 4), 256, 0, stream>>>(xh, xl, Wqh, Wql, qbf);
  gemm_nt<true, 0><<<dim3(64, 4), 256, 0, stream>>>(xh, xl, Wkh, Wkl, kbf);
  gemm_nt<false, 1><<<dim3(64, 4), 256, 0, stream>>>(xh, xh, Wvh, Wvh, vtb);
  attn_fused<<<dim3(T_SEQ / QT, NHEAD, 4), 512, 0, stream>>>(
      qbf, kbf, vtb, mask, attn_out, ctx);
  gemm_nt<false, 2><<<dim3(64, 4), 256, 0, stream>>>(ctx, ctx, Woh, Woh, xout);
}